// Round 7
// baseline (12778.962 us; speedup 1.0000x reference)
//
#include <hip/hip_runtime.h>
#include <cstdint>
#include <cstddef>

// Problem constants (LSTM_66726611911224)
#define TT   2048
#define BB   64
#define IND  128
#define HH   256
#define GG   1024   // 4*H, gate order i,f,g,o
#define OUTD 128
#define TC   128    // time-chunk size
#define NCH  (TT / TC)

// ---- workspace layout (bytes) ----
static const size_t XG_OFF     = 0;                         // f16 [TC*B][1024] = 16,777,216
static const size_t WHH_OFF    = 16777216ull;               // uint4 [4][2][16][256] = 524,288
static const size_t WIH_OFF    = WHH_OFF  + 524288ull;      // uint4 [16384]    =    262,144
static const size_t WOUT_OFF   = WIH_OFF  + 262144ull;      // f16 [128][256]   =     65,536
static const size_t BSUM_OFF   = WOUT_OFF + 65536ull;       // f32 [1024]       =      4,096
static const size_t HSTATE_OFF = BSUM_OFF + 4096ull;        // f16 [64][256]    =     32,768
static const size_t CSTATE_OFF = HSTATE_OFF + 32768ull;     // f32 [64][256]    =     65,536
static const size_t WS_NEEDED  = CSTATE_OFF + 65536ull;     // = 17,731,584

typedef _Float16 h2 __attribute__((ext_vector_type(2)));

union U16 { uint4 u; h2 h[4]; };          // 16B <-> 4x half2
union HU  { unsigned short u; _Float16 h; };

__device__ __forceinline__ float fdot2f(h2 a, h2 b, float c) {
#if __has_builtin(__builtin_amdgcn_fdot2)
  return __builtin_amdgcn_fdot2(a, b, c, false);   // v_dot2_f32_f16, f32 accumulate
#else
  return c + (float)a.x * (float)b.x + (float)a.y * (float)b.y;
#endif
}

__device__ __forceinline__ float sigm(float x) { return 1.f / (1.f + __expf(-x)); }
__device__ __forceinline__ float tanh_fast(float x) {
  float ax = fabsf(x);
  float e  = __expf(-2.f * ax);          // in (0,1], no overflow
  float r  = (1.f - e) / (1.f + e);
  return x < 0.f ? -r : r;
}

// ---------------- K0: pack weights to f16 layouts, bias sum ----------------
// W_hh layout for k2: uint4 index = rr*8192 + half*4096 + q*256 + u
//   rr 0/1/2/3 -> rows u / 256+u / 768+u / 512+u  (i, f, o, g)
//   k-range of the uint4: half*128 + q*8 .. +8
__global__ void k0_pack(const float* __restrict__ Whh, const float* __restrict__ Wih,
                        const float* __restrict__ Wout, const float* __restrict__ bih,
                        const float* __restrict__ bhh, uint8_t* __restrict__ ws) {
  int tid = blockIdx.x * 256 + threadIdx.x;
  if (tid < 32768) {
    int rr = tid >> 13, rem = tid & 8191;
    int hf = rem >> 12, q = (rem >> 8) & 15, u = rem & 255;
    int row = (rr == 0) ? u : (rr == 1) ? 256 + u : (rr == 2) ? 768 + u : 512 + u;
    int kb = hf * 128 + q * 8;
    const float4* s = (const float4*)(Whh + (size_t)row * HH + kb);
    float4 v0 = s[0], v1 = s[1];
    U16 o;
    o.h[0].x = (_Float16)v0.x; o.h[0].y = (_Float16)v0.y;
    o.h[1].x = (_Float16)v0.z; o.h[1].y = (_Float16)v0.w;
    o.h[2].x = (_Float16)v1.x; o.h[2].y = (_Float16)v1.y;
    o.h[3].x = (_Float16)v1.z; o.h[3].y = (_Float16)v1.w;
    ((uint4*)(ws + WHH_OFF))[tid] = o.u;
  } else if (tid < 65536) {                // W_out -> f16, row-major [128][256]
    int t2 = tid - 32768;
    ((_Float16*)(ws + WOUT_OFF))[t2] = (_Float16)Wout[t2];
  } else if (tid < 81920) {                // W_ih -> f16, row-major [1024][128], 8-packed
    int i = tid - 65536;
    const float4* s = (const float4*)(Wih + (size_t)i * 8);
    float4 v0 = s[0], v1 = s[1];
    U16 o;
    o.h[0].x = (_Float16)v0.x; o.h[0].y = (_Float16)v0.y;
    o.h[1].x = (_Float16)v0.z; o.h[1].y = (_Float16)v0.w;
    o.h[2].x = (_Float16)v1.x; o.h[2].y = (_Float16)v1.y;
    o.h[3].x = (_Float16)v1.z; o.h[3].y = (_Float16)v1.w;
    ((uint4*)(ws + WIH_OFF))[i] = o.u;
  } else if (tid < 82944) {                // bias sum
    int n = tid - 81920;
    ((float*)(ws + BSUM_OFF))[n] = bih[n] + bhh[n];
  }
}

// ---------------- K1: xg chunk = x @ W_ih^T + (b_ih+b_hh), f16 out ----------------
__global__ void __launch_bounds__(256) k1_xgemm(const float* __restrict__ x,
                                                uint8_t* __restrict__ ws, int t0) {
  const uint4* Wp   = (const uint4*)(ws + WIH_OFF);
  const float* bsum = (const float*)(ws + BSUM_OFF);
  _Float16*    xg   = (_Float16*)(ws + XG_OFF);

  const int s = blockIdx.x >> 5;                       // col segment (64 cols)
  const int m = ((blockIdx.x & 31) << 8) + threadIdx.x;

  __shared__ uint4 wlds[1024];                         // 64 rows x 16 uint4
  __shared__ float bsl[64];
  #pragma unroll
  for (int i = 0; i < 4; ++i)
    wlds[i * 256 + threadIdx.x] = Wp[(size_t)(s << 6) * 16 + i * 256 + threadIdx.x];
  if (threadIdx.x < 64) bsl[threadIdx.x] = bsum[(s << 6) + threadIdx.x];
  __syncthreads();

  const float4* xr = (const float4*)(x + ((size_t)t0 * BB + m) * IND);
  h2 xv[64];
  #pragma unroll
  for (int i = 0; i < 32; ++i) {
    float4 v = xr[i];
    xv[2*i  ].x = (_Float16)v.x; xv[2*i  ].y = (_Float16)v.y;
    xv[2*i+1].x = (_Float16)v.z; xv[2*i+1].y = (_Float16)v.w;
  }
  _Float16* xgrow = xg + (size_t)m * GG + (s << 6);
  for (int g = 0; g < 8; ++g) {
    float acc[8];
    #pragma unroll
    for (int j = 0; j < 8; ++j) {
      const uint4* wr = &wlds[(g * 8 + j) * 16];
      float a = bsl[g * 8 + j];
      #pragma unroll
      for (int q = 0; q < 16; ++q) {
        U16 w; w.u = wr[q];
        a = fdot2f(w.h[0], xv[4*q+0], a);
        a = fdot2f(w.h[1], xv[4*q+1], a);
        a = fdot2f(w.h[2], xv[4*q+2], a);
        a = fdot2f(w.h[3], xv[4*q+3], a);
      }
      acc[j] = a;
    }
    U16 o;
    #pragma unroll
    for (int p = 0; p < 4; ++p) { o.h[p].x = (_Float16)acc[2*p]; o.h[p].y = (_Float16)acc[2*p+1]; }
    *(uint4*)(xgrow + g * 8) = o.u;
  }
}

// ---------------- K2: recurrence chunk + fused output projection ----------------
// 512 threads / wg, 1 wg per batch element. u=tid&255, half=tid>>8.
// ALL of W_hh register-resident (4 x 64 h2 per thread, AGPR-backed).
// Fused y: thread also computes a quarter-k partial of y[col=u&127] from the
// PREVIOUS step's h (already in hv regs), exchanged via LDS inside the same
// barrier pair; threads 256..383 finalize+store y. No h-history, no k3.
__global__ void __launch_bounds__(512, 2) k2_recur(uint8_t* __restrict__ ws,
                                                   const float* __restrict__ b_out,
                                                   float* __restrict__ out, int t0) {
  const int tid  = threadIdx.x;
  const int b    = blockIdx.x;
  const int u    = tid & 255;
  const int half = tid >> 8;
  const int kq   = u >> 7;                  // k-quarter selector for y
  const int col  = u & 127;                 // y output column
  const int kqs  = __builtin_amdgcn_readfirstlane(kq);  // wave-uniform

  const uint4* WR = (const uint4*)(ws + WHH_OFF);
  const uint4* WO = (const uint4*)(ws + WOUT_OFF);    // [128][32] uint4
  const unsigned short* xp = (const unsigned short*)(ws + XG_OFF);
  _Float16* hstate = (_Float16*)(ws + HSTATE_OFF);
  float*    cstate = (float*)(ws + CSTATE_OFF);

  __shared__ alignas(16) _Float16 h_lds[HH];               // 512 B
  __shared__ float ps_i[256], ps_f[256], ps_g[256], ps_o[256]; // 4 KB gate partials
  __shared__ float py[512];                                // 2 KB y partials

  // ---- one-time: all W_hh rows for this (u,half) into registers (AGPRs) ----
  h2 wi[64], wf[64], wo[64], wg[64];
  #pragma unroll
  for (int q = 0; q < 16; ++q) {
    U16 a;
    a.u = WR[(size_t)((0 * 2 + half) * 16 + q) * 256 + u];
    wi[4*q+0]=a.h[0]; wi[4*q+1]=a.h[1]; wi[4*q+2]=a.h[2]; wi[4*q+3]=a.h[3];
    a.u = WR[(size_t)((1 * 2 + half) * 16 + q) * 256 + u];
    wf[4*q+0]=a.h[0]; wf[4*q+1]=a.h[1]; wf[4*q+2]=a.h[2]; wf[4*q+3]=a.h[3];
    a.u = WR[(size_t)((2 * 2 + half) * 16 + q) * 256 + u];
    wo[4*q+0]=a.h[0]; wo[4*q+1]=a.h[1]; wo[4*q+2]=a.h[2]; wo[4*q+3]=a.h[3];
    a.u = WR[(size_t)((3 * 2 + half) * 16 + q) * 256 + u];
    wg[4*q+0]=a.h[0]; wg[4*q+1]=a.h[1]; wg[4*q+2]=a.h[2]; wg[4*q+3]=a.h[3];
  }
  // W_out quarter-row for y: k range = half*128 + kq*64
  h2 wy[32];
  #pragma unroll
  for (int j = 0; j < 8; ++j) {
    U16 a; a.u = WO[(size_t)col * 32 + half * 16 + kq * 8 + j];
    wy[4*j+0]=a.h[0]; wy[4*j+1]=a.h[1]; wy[4*j+2]=a.h[2]; wy[4*j+3]=a.h[3];
  }
  float bo = (tid >= 256 && tid < 384) ? b_out[tid - 256] : 0.f;

  if (tid < 32) {
    uint4 z = make_uint4(0u, 0u, 0u, 0u);
    ((uint4*)h_lds)[tid] = (t0 == 0) ? z : ((const uint4*)(hstate + (size_t)b * HH))[tid];
  }
  float c = 0.f;
  if (half == 0 && t0 != 0) c = cstate[(size_t)b * HH + u];

  const size_t xrow = (size_t)b * GG;
  HU xi, xf, xgv, xo;
  if (half == 0) {
    xi.u  = xp[xrow + u];
    xf.u  = xp[xrow + 256 + u];
    xgv.u = xp[xrow + 512 + u];
    xo.u  = xp[xrow + 768 + u];
  }
  __syncthreads();

  for (int tt = 0; tt < TC; ++tt) {
    float ai = 0.f, af = 0.f, ag = 0.f, ao = 0.f, ay = 0.f;
    const uint4* hv = ((const uint4*)h_lds) + half * 16;
    #pragma unroll
    for (int q = 0; q < 16; ++q) {
      U16 hh; hh.u = hv[q];                          // wave-uniform broadcast
      #pragma unroll
      for (int j = 0; j < 4; ++j) {
        ai = fdot2f(wi[4*q+j], hh.h[j], ai);
        af = fdot2f(wf[4*q+j], hh.h[j], af);
        ag = fdot2f(wg[4*q+j], hh.h[j], ag);
        ao = fdot2f(wo[4*q+j], hh.h[j], ao);
      }
      if ((q >> 3) == kqs) {                         // y quarter (scalar branch)
        const int j0 = 4 * (q & 7);
        ay = fdot2f(wy[j0+0], hh.h[0], ay);
        ay = fdot2f(wy[j0+1], hh.h[1], ay);
        ay = fdot2f(wy[j0+2], hh.h[2], ay);
        ay = fdot2f(wy[j0+3], hh.h[3], ay);
      }
    }
    py[(half * 2 + kq) * 128 + col] = ay;            // y_{tt-1} partial
    if (half == 1) { ps_i[u] = ai; ps_f[u] = af; ps_g[u] = ag; ps_o[u] = ao; }
    __syncthreads();                                 // partials visible; h reads done
    if (tt >= 1 && tid >= 256 && tid < 384) {        // finalize y_{t0+tt-1}
      const int oo = tid - 256;
      float v = py[oo] + py[128 + oo] + py[256 + oo] + py[384 + oo] + bo;
      out[((size_t)(t0 + tt - 1) * BB + b) * OUTD + oo] = v;
    }
    if (half == 0) {
      float gi = sigm(ai + ps_i[u] + (float)xi.h);
      float gf = sigm(af + ps_f[u] + (float)xf.h);
      float gg = tanh_fast(ag + ps_g[u] + (float)xgv.h);
      float go = sigm(ao + ps_o[u] + (float)xo.h);
      c = gf * c + gi * gg;
      float hn = go * tanh_fast(c);
      h_lds[u] = (_Float16)hn;
      if (tt + 1 < TC) {
        const size_t nx = xrow + (size_t)(tt + 1) * (BB * GG);
        xi.u  = xp[nx + u];
        xf.u  = xp[nx + 256 + u];
        xgv.u = xp[nx + 512 + u];
        xo.u  = xp[nx + 768 + u];
      }
      if (t0 + tt == TT - 1) {
        const size_t tail = (size_t)TT * BB * OUTD;
        out[tail + (size_t)b * HH + u] = hn;                       // h_T
        out[tail + (size_t)BB * HH + (size_t)b * HH + u] = c;      // c_T
      }
    }
    __syncthreads();                                 // new h visible
  }

  // ---- epilogue: y for the chunk's last step (h_lds = h_{t0+TC-1}) ----
  {
    float ay = 0.f;
    const uint4* hv = ((const uint4*)h_lds) + half * 16;
    #pragma unroll
    for (int q = 0; q < 16; ++q) {
      if ((q >> 3) == kqs) {
        U16 hh; hh.u = hv[q];
        const int j0 = 4 * (q & 7);
        ay = fdot2f(wy[j0+0], hh.h[0], ay);
        ay = fdot2f(wy[j0+1], hh.h[1], ay);
        ay = fdot2f(wy[j0+2], hh.h[2], ay);
        ay = fdot2f(wy[j0+3], hh.h[3], ay);
      }
    }
    py[(half * 2 + kq) * 128 + col] = ay;
    __syncthreads();
    if (tid >= 256 && tid < 384) {
      const int oo = tid - 256;
      float v = py[oo] + py[128 + oo] + py[256 + oo] + py[384 + oo] + bo;
      out[((size_t)(t0 + TC - 1) * BB + b) * OUTD + oo] = v;
    }
  }

  if (tid < 32) ((uint4*)(hstate + (size_t)b * HH))[tid] = ((const uint4*)h_lds)[tid];
  if (half == 0) cstate[(size_t)b * HH + u] = c;
}

extern "C" void kernel_launch(void* const* d_in, const int* in_sizes, int n_in,
                              void* d_out, int out_size, void* d_ws, size_t ws_size,
                              hipStream_t stream) {
  const float* input = (const float*)d_in[0];
  const float* W_ih  = (const float*)d_in[1];
  const float* W_hh  = (const float*)d_in[2];
  const float* b_ih  = (const float*)d_in[3];
  const float* b_hh  = (const float*)d_in[4];
  const float* W_out = (const float*)d_in[5];
  const float* b_out = (const float*)d_in[6];
  float*   out = (float*)d_out;
  uint8_t* ws  = (uint8_t*)d_ws;

  if (ws_size < WS_NEEDED) return;   // fail validation cleanly instead of faulting

  hipLaunchKernelGGL(k0_pack, dim3(324), dim3(256), 0, stream,
                     W_hh, W_ih, W_out, b_ih, b_hh, ws);
  for (int ch = 0; ch < NCH; ++ch) {
    const int t0 = ch * TC;
    hipLaunchKernelGGL(k1_xgemm, dim3(512), dim3(256), 0, stream, input, ws, t0);
    hipLaunchKernelGGL(k2_recur, dim3(64),  dim3(512), 0, stream, ws, b_out, out, t0);
  }
}

// Round 8
// 4374.982 us; speedup vs baseline: 2.9209x; 2.9209x over previous
//
#include <hip/hip_runtime.h>
#include <cstdint>
#include <cstddef>

// Problem constants (LSTM_66726611911224)
#define TT   2048
#define BB   64
#define IND  128
#define HH   256
#define GG   1024   // 4*H, gate order i,f,g,o
#define OUTD 128
#define TC   64     // time-chunk size
#define NCH  (TT / TC)   // 32

// ---- workspace layout (bytes), total = 21,925,888 (proven available) ----
static const size_t XG0_OFF    = 0;                         // f16 [TC*B][1024] = 8,388,608
static const size_t XG1_OFF    = 8388608ull;                // f16 [TC*B][1024] = 8,388,608
static const size_t HST0_OFF   = 16777216ull;               // f16 [TC*B][256]  = 2,097,152
static const size_t HST1_OFF   = 18874368ull;               // f16 [TC*B][256]  = 2,097,152
static const size_t WHH_OFF    = 20971520ull;               // uint4 [4][2][16][256] = 524,288
static const size_t WIH_OFF    = WHH_OFF  + 524288ull;      // uint4 [16384]    =    262,144
static const size_t WOUT_OFF   = WIH_OFF  + 262144ull;      // f16 [128][256]   =     65,536
static const size_t BSUM_OFF   = WOUT_OFF + 65536ull;       // f32 [1024]       =      4,096
static const size_t HSTATE_OFF = BSUM_OFF + 4096ull;        // f16 [64][256]    =     32,768
static const size_t CSTATE_OFF = HSTATE_OFF + 32768ull;     // f32 [64][256]    =     65,536
static const size_t WS_NEEDED  = CSTATE_OFF + 65536ull;     // = 21,925,888

// fused-kernel dynamic LDS: consumer role is the max user
static const int SMEM_SZ = 65536 + 512 + 4096;              // gws + h_lds + partials = 70,144

typedef _Float16 h2 __attribute__((ext_vector_type(2)));

union U16 { uint4 u; h2 h[4]; };          // 16B <-> 4x half2
union HU  { unsigned short u; _Float16 h; };

__device__ __forceinline__ float fdot2f(h2 a, h2 b, float c) {
#if __has_builtin(__builtin_amdgcn_fdot2)
  return __builtin_amdgcn_fdot2(a, b, c, false);   // v_dot2_f32_f16, f32 accumulate
#else
  return c + (float)a.x * (float)b.x + (float)a.y * (float)b.y;
#endif
}

__device__ __forceinline__ float sigm(float x) { return 1.f / (1.f + __expf(-x)); }
__device__ __forceinline__ float tanh_fast(float x) {
  float ax = fabsf(x);
  float e  = __expf(-2.f * ax);          // in (0,1], no overflow
  float r  = (1.f - e) / (1.f + e);
  return x < 0.f ? -r : r;
}

// ---------------- K0: pack weights to f16 layouts, bias sum ----------------
// W_hh layout: uint4 index = rr*8192 + half*4096 + q*256 + u
//   rr 0/1/2/3 -> rows u / 256+u / 768+u / 512+u  (i, f, o, g)
//   k-range of the uint4: half*128 + q*8 .. +8
__global__ void k0_pack(const float* __restrict__ Whh, const float* __restrict__ Wih,
                        const float* __restrict__ Wout, const float* __restrict__ bih,
                        const float* __restrict__ bhh, uint8_t* __restrict__ ws) {
  int tid = blockIdx.x * 256 + threadIdx.x;
  if (tid < 32768) {
    int rr = tid >> 13, rem = tid & 8191;
    int hf = rem >> 12, q = (rem >> 8) & 15, u = rem & 255;
    int row = (rr == 0) ? u : (rr == 1) ? 256 + u : (rr == 2) ? 768 + u : 512 + u;
    int kb = hf * 128 + q * 8;
    const float4* s = (const float4*)(Whh + (size_t)row * HH + kb);
    float4 v0 = s[0], v1 = s[1];
    U16 o;
    o.h[0].x = (_Float16)v0.x; o.h[0].y = (_Float16)v0.y;
    o.h[1].x = (_Float16)v0.z; o.h[1].y = (_Float16)v0.w;
    o.h[2].x = (_Float16)v1.x; o.h[2].y = (_Float16)v1.y;
    o.h[3].x = (_Float16)v1.z; o.h[3].y = (_Float16)v1.w;
    ((uint4*)(ws + WHH_OFF))[tid] = o.u;
  } else if (tid < 65536) {                // W_out -> f16, row-major [128][256]
    int t2 = tid - 32768;
    ((_Float16*)(ws + WOUT_OFF))[t2] = (_Float16)Wout[t2];
  } else if (tid < 81920) {                // W_ih -> f16, row-major [1024][128], 8-packed
    int i = tid - 65536;
    const float4* s = (const float4*)(Wih + (size_t)i * 8);
    float4 v0 = s[0], v1 = s[1];
    U16 o;
    o.h[0].x = (_Float16)v0.x; o.h[0].y = (_Float16)v0.y;
    o.h[1].x = (_Float16)v0.z; o.h[1].y = (_Float16)v0.w;
    o.h[2].x = (_Float16)v1.x; o.h[2].y = (_Float16)v1.y;
    o.h[3].x = (_Float16)v1.z; o.h[3].y = (_Float16)v1.w;
    ((uint4*)(ws + WIH_OFF))[i] = o.u;
  } else if (tid < 82944) {                // bias sum
    int n = tid - 81920;
    ((float*)(ws + BSUM_OFF))[n] = bih[n] + bhh[n];
  }
}

// ---------------- K1: xg for chunk 0 only (later chunks made by producer wgs) ----
__global__ void __launch_bounds__(256) k1_xgemm(const float* __restrict__ x,
                                                uint8_t* __restrict__ ws) {
  const uint4* Wp   = (const uint4*)(ws + WIH_OFF);
  const float* bsum = (const float*)(ws + BSUM_OFF);
  _Float16*    xg   = (_Float16*)(ws + XG0_OFF);

  const int s = blockIdx.x >> 4;                       // col segment (64 cols), 16 segs
  const int m = ((blockIdx.x & 15) << 8) + threadIdx.x; // row 0..4095

  __shared__ uint4 wlds[1024];                         // 64 rows x 16 uint4
  __shared__ float bsl[64];
  #pragma unroll
  for (int i = 0; i < 4; ++i)
    wlds[i * 256 + threadIdx.x] = Wp[(size_t)(s << 6) * 16 + i * 256 + threadIdx.x];
  if (threadIdx.x < 64) bsl[threadIdx.x] = bsum[(s << 6) + threadIdx.x];
  __syncthreads();

  const float4* xr = (const float4*)(x + (size_t)m * IND);   // t0 = 0
  h2 xv[64];
  #pragma unroll
  for (int i = 0; i < 32; ++i) {
    float4 v = xr[i];
    xv[2*i  ].x = (_Float16)v.x; xv[2*i  ].y = (_Float16)v.y;
    xv[2*i+1].x = (_Float16)v.z; xv[2*i+1].y = (_Float16)v.w;
  }
  _Float16* xgrow = xg + (size_t)m * GG + (s << 6);
  for (int g = 0; g < 8; ++g) {
    float acc[8];
    #pragma unroll
    for (int j = 0; j < 8; ++j) {
      const uint4* wr = &wlds[(g * 8 + j) * 16];
      float a = bsl[g * 8 + j];
      #pragma unroll
      for (int q = 0; q < 16; ++q) {
        U16 w; w.u = wr[q];
        a = fdot2f(w.h[0], xv[4*q+0], a);
        a = fdot2f(w.h[1], xv[4*q+1], a);
        a = fdot2f(w.h[2], xv[4*q+2], a);
        a = fdot2f(w.h[3], xv[4*q+3], a);
      }
      acc[j] = a;
    }
    U16 o;
    #pragma unroll
    for (int p = 0; p < 4; ++p) { o.h[p].x = (_Float16)acc[2*p]; o.h[p].y = (_Float16)acc[2*p+1]; }
    *(uint4*)(xgrow + g * 8) = o.u;
  }
}

// ---------------- Fused per-chunk kernel: 3 wg roles ----------------
// grid 224 x 512 threads:
//   wg 0..63    consumer : recurrence for chunk ch (1 wg per batch element)
//   wg 64..191  producer : xg GEMM for chunk ch+1 (ping-pong buffer)
//   wg 192..223+ y       : output projection of chunk ch-1 from hst ping-pong
// Consumer register layout = round-5 proven no-spill: i/f/o half-rows in
// 192 regs; g half-rows split 8q from 64KB LDS + 8q streamed from L2.
__global__ void __launch_bounds__(512, 2) k2_fused(const float* __restrict__ x,
                                                   uint8_t* __restrict__ ws,
                                                   const float* __restrict__ b_out,
                                                   float* __restrict__ out, int ch) {
  extern __shared__ __align__(16) uint8_t smem[];
  const int bi  = blockIdx.x;
  const int tid = threadIdx.x;

  if (bi < 64) {
    // ================= consumer =================
    if (ch >= NCH) return;
    const int b    = bi;
    const int u    = tid & 255;
    const int half = tid >> 8;
    const int t0   = ch * TC;

    const uint4* WR = (const uint4*)(ws + WHH_OFF);
    const uint4* WG = WR + 24576;                     // g rows [2][16][256]
    const unsigned short* xp = (const unsigned short*)(ws + ((ch & 1) ? XG1_OFF : XG0_OFF));
    _Float16* hst    = (_Float16*)(ws + ((ch & 1) ? HST1_OFF : HST0_OFF));
    _Float16* hstate = (_Float16*)(ws + HSTATE_OFF);
    float*    cstate = (float*)(ws + CSTATE_OFF);

    uint4*    gws   = (uint4*)smem;                   // [2][8][256] uint4 = 64 KB (g, q0..7)
    _Float16* h_lds = (_Float16*)(smem + 65536);      // 512 B
    float*    ps_i  = (float*)(smem + 65536 + 512);   // 4 x 1 KB partials
    float*    ps_f  = ps_i + 256;
    float*    ps_g  = ps_f + 256;
    float*    ps_o  = ps_g + 256;

    // one-time: i/f/o half-rows into registers (192 h2)
    h2 wi[64], wf[64], wo[64];
    #pragma unroll
    for (int q = 0; q < 16; ++q) {
      U16 a;
      a.u = WR[(size_t)((0 * 2 + half) * 16 + q) * 256 + u];
      wi[4*q+0]=a.h[0]; wi[4*q+1]=a.h[1]; wi[4*q+2]=a.h[2]; wi[4*q+3]=a.h[3];
      a.u = WR[(size_t)((1 * 2 + half) * 16 + q) * 256 + u];
      wf[4*q+0]=a.h[0]; wf[4*q+1]=a.h[1]; wf[4*q+2]=a.h[2]; wf[4*q+3]=a.h[3];
      a.u = WR[(size_t)((2 * 2 + half) * 16 + q) * 256 + u];
      wo[4*q+0]=a.h[0]; wo[4*q+1]=a.h[1]; wo[4*q+2]=a.h[2]; wo[4*q+3]=a.h[3];
    }
    // one-time: stage g q0..7 (both halves) into LDS
    #pragma unroll
    for (int j = 0; j < 8; ++j) {
      int idx = j * 512 + tid;                        // [half'][q'][u']
      int hf = idx >> 11, q2 = (idx >> 8) & 7, u2 = idx & 255;
      gws[idx] = WG[(size_t)(hf * 16 + q2) * 256 + u2];
    }
    const uint4* gl  = gws + half * 2048 + u;         // LDS g, element q: gl[q*256]
    const uint4* wgp = WG + (size_t)(half * 16) * 256 + u;  // global g, q8..15

    if (tid < 32) {
      uint4 z = make_uint4(0u, 0u, 0u, 0u);
      ((uint4*)h_lds)[tid] = (t0 == 0) ? z : ((const uint4*)(hstate + (size_t)b * HH))[tid];
    }
    float c = 0.f;
    if (half == 0 && t0 != 0) c = cstate[(size_t)b * HH + u];

    const size_t xrow = (size_t)b * GG;
    HU xi, xf, xgv, xo;
    if (half == 0) {
      xi.u  = xp[xrow + u];
      xf.u  = xp[xrow + 256 + u];
      xgv.u = xp[xrow + 512 + u];
      xo.u  = xp[xrow + 768 + u];
    }
    __syncthreads();

    for (int tt = 0; tt < TC; ++tt) {
      float ai = 0.f, af = 0.f, ag = 0.f, ao = 0.f;
      const uint4* hv = ((const uint4*)h_lds) + half * 16;
      #pragma unroll
      for (int q = 0; q < 8; ++q) {                   // g from LDS
        U16 hh;  hh.u  = hv[q];
        U16 wg_; wg_.u = gl[q * 256];
        #pragma unroll
        for (int j = 0; j < 4; ++j) {
          ai = fdot2f(wi[4*q+j], hh.h[j], ai);
          af = fdot2f(wf[4*q+j], hh.h[j], af);
          ag = fdot2f(wg_.h[j],  hh.h[j], ag);
          ao = fdot2f(wo[4*q+j], hh.h[j], ao);
        }
      }
      #pragma unroll
      for (int q = 8; q < 16; ++q) {                  // g streamed from L2
        U16 hh;  hh.u  = hv[q];
        U16 wg_; wg_.u = wgp[(size_t)q * 256];
        #pragma unroll
        for (int j = 0; j < 4; ++j) {
          ai = fdot2f(wi[4*q+j], hh.h[j], ai);
          af = fdot2f(wf[4*q+j], hh.h[j], af);
          ag = fdot2f(wg_.h[j],  hh.h[j], ag);
          ao = fdot2f(wo[4*q+j], hh.h[j], ao);
        }
      }
      if (half == 1) { ps_i[u] = ai; ps_f[u] = af; ps_g[u] = ag; ps_o[u] = ao; }
      __syncthreads();                                // partials visible; h reads done
      if (half == 0) {
        float gi = sigm(ai + ps_i[u] + (float)xi.h);
        float gf = sigm(af + ps_f[u] + (float)xf.h);
        float gg = tanh_fast(ag + ps_g[u] + (float)xgv.h);
        float go = sigm(ao + ps_o[u] + (float)xo.h);
        c = gf * c + gi * gg;
        float hn = go * tanh_fast(c);
        h_lds[u] = (_Float16)hn;
        hst[((size_t)tt * BB + b) * HH + u] = (_Float16)hn;
        if (tt + 1 < TC) {
          const size_t nx = xrow + (size_t)(tt + 1) * (BB * GG);
          xi.u  = xp[nx + u];
          xf.u  = xp[nx + 256 + u];
          xgv.u = xp[nx + 512 + u];
          xo.u  = xp[nx + 768 + u];
        }
        if (t0 + tt == TT - 1) {
          const size_t tail = (size_t)TT * BB * OUTD;
          out[tail + (size_t)b * HH + u] = hn;                       // h_T
          out[tail + (size_t)BB * HH + (size_t)b * HH + u] = c;      // c_T
        }
      }
      __syncthreads();                                // new h visible
    }

    if (tid < 32) ((uint4*)(hstate + (size_t)b * HH))[tid] = ((const uint4*)h_lds)[tid];
    if (half == 0) cstate[(size_t)b * HH + u] = c;

  } else if (bi < 192) {
    // ================= producer: xg for chunk ch+1 =================
    if (ch + 1 >= NCH) return;
    const int p    = bi - 64;
    const int seg  = p >> 3;                          // 0..15 (64-col segment)
    const int rowg = p & 7;
    const int m    = rowg * 512 + tid;                // 0..4095
    const int t0n  = (ch + 1) * TC;

    const uint4* Wp   = (const uint4*)(ws + WIH_OFF);
    const float* bsum = (const float*)(ws + BSUM_OFF);
    _Float16*    xgn  = (_Float16*)(ws + (((ch + 1) & 1) ? XG1_OFF : XG0_OFF));

    uint4* wlds = (uint4*)smem;                       // 1024 uint4 = 16 KB
    float* bsl  = (float*)(smem + 16384);
    wlds[tid]       = Wp[(size_t)(seg << 6) * 16 + tid];
    wlds[tid + 512] = Wp[(size_t)(seg << 6) * 16 + 512 + tid];
    if (tid < 64) bsl[tid] = bsum[(seg << 6) + tid];
    __syncthreads();

    const float4* xr = (const float4*)(x + ((size_t)t0n * BB + m) * IND);
    h2 xv[64];
    #pragma unroll
    for (int i = 0; i < 32; ++i) {
      float4 v = xr[i];
      xv[2*i  ].x = (_Float16)v.x; xv[2*i  ].y = (_Float16)v.y;
      xv[2*i+1].x = (_Float16)v.z; xv[2*i+1].y = (_Float16)v.w;
    }
    _Float16* xgrow = xgn + (size_t)m * GG + (seg << 6);
    for (int g = 0; g < 8; ++g) {
      float acc[8];
      #pragma unroll
      for (int j = 0; j < 8; ++j) {
        const uint4* wr = &wlds[(g * 8 + j) * 16];
        float a = bsl[g * 8 + j];
        #pragma unroll
        for (int q = 0; q < 16; ++q) {
          U16 w; w.u = wr[q];
          a = fdot2f(w.h[0], xv[4*q+0], a);
          a = fdot2f(w.h[1], xv[4*q+1], a);
          a = fdot2f(w.h[2], xv[4*q+2], a);
          a = fdot2f(w.h[3], xv[4*q+3], a);
        }
        acc[j] = a;
      }
      U16 o;
      #pragma unroll
      for (int pk = 0; pk < 4; ++pk) { o.h[pk].x = (_Float16)acc[2*pk]; o.h[pk].y = (_Float16)acc[2*pk+1]; }
      *(uint4*)(xgrow + g * 8) = o.u;
    }

  } else {
    // ================= y: output projection for chunk ch-1 =================
    if (ch < 1) return;
    const int yb   = bi - 192;                        // 0..31
    const int seg  = yb & 15;                         // 8-col segment
    const int rowg = yb >> 4;                         // 0..1
    const int t0p  = (ch - 1) * TC;

    const _Float16* hstp = (const _Float16*)(ws + (((ch - 1) & 1) ? HST1_OFF : HST0_OFF));
    const uint4* WO = (const uint4*)(ws + WOUT_OFF);  // [128][32] uint4

    uint4* wlds = (uint4*)smem;                       // 256 uint4 = 4 KB
    float* bsl  = (float*)(smem + 4096);
    if (tid < 256) wlds[tid] = WO[(size_t)(seg * 8) * 32 + tid];
    if (tid < 8)   bsl[tid]  = b_out[seg * 8 + tid];
    __syncthreads();

    #pragma unroll
    for (int rr = 0; rr < 4; ++rr) {                  // 4 rows per thread
      const int r = rowg * 2048 + rr * 512 + tid;     // 0..4095
      const uint4* hr = (const uint4*)(hstp + (size_t)r * HH);
      float acc[8];
      #pragma unroll
      for (int j = 0; j < 8; ++j) acc[j] = bsl[j];
      #pragma unroll 4
      for (int q = 0; q < 32; ++q) {
        U16 hh; hh.u = hr[q];
        #pragma unroll
        for (int j = 0; j < 8; ++j) {
          U16 w; w.u = wlds[j * 32 + q];
          acc[j] = fdot2f(w.h[0], hh.h[0], acc[j]);
          acc[j] = fdot2f(w.h[1], hh.h[1], acc[j]);
          acc[j] = fdot2f(w.h[2], hh.h[2], acc[j]);
          acc[j] = fdot2f(w.h[3], hh.h[3], acc[j]);
        }
      }
      float* orow = out + ((size_t)t0p * BB + r) * OUTD + seg * 8;
      *(float4*)(orow)     = make_float4(acc[0], acc[1], acc[2], acc[3]);
      *(float4*)(orow + 4) = make_float4(acc[4], acc[5], acc[6], acc[7]);
    }
  }
}

extern "C" void kernel_launch(void* const* d_in, const int* in_sizes, int n_in,
                              void* d_out, int out_size, void* d_ws, size_t ws_size,
                              hipStream_t stream) {
  const float* input = (const float*)d_in[0];
  const float* W_ih  = (const float*)d_in[1];
  const float* W_hh  = (const float*)d_in[2];
  const float* b_ih  = (const float*)d_in[3];
  const float* b_hh  = (const float*)d_in[4];
  const float* W_out = (const float*)d_in[5];
  const float* b_out = (const float*)d_in[6];
  float*   out = (float*)d_out;
  uint8_t* ws  = (uint8_t*)d_ws;

  if (ws_size < WS_NEEDED) return;   // fail validation cleanly instead of faulting

  // allow 70.1 KB dynamic LDS (gfx950: 160 KB/CU); host-side + idempotent ->
  // safe under graph capture (proven round 5).
  hipFuncSetAttribute((const void*)k2_fused,
                      hipFuncAttributeMaxDynamicSharedMemorySize, SMEM_SZ);

  hipLaunchKernelGGL(k0_pack,  dim3(324), dim3(256), 0, stream,
                     W_hh, W_ih, W_out, b_ih, b_hh, ws);
  hipLaunchKernelGGL(k1_xgemm, dim3(256), dim3(256), 0, stream, input, ws); // chunk 0 xg
  for (int ch = 0; ch <= NCH; ++ch) {   // ch==NCH: only y-role (last chunk's output)
    hipLaunchKernelGGL(k2_fused, dim3(224), dim3(512), SMEM_SZ, stream,
                       input, ws, b_out, out, ch);
  }
}

// Round 9
// 3720.398 us; speedup vs baseline: 3.4348x; 1.1759x over previous
//
#include <hip/hip_runtime.h>
#include <cstdint>
#include <cstddef>

// Problem constants (LSTM_66726611911224)
#define TT   2048
#define BB   64
#define IND  128
#define HH   256
#define GG   1024   // 4*H, gate order i,f,g,o
#define OUTD 128
#define TC   64     // time-chunk size
#define NCH  (TT / TC)   // 32

// ---- workspace layout (bytes), total = 21,925,888 (proven available) ----
static const size_t XG0_OFF    = 0;                         // f16 [TC*B][1024] = 8,388,608
static const size_t XG1_OFF    = 8388608ull;                // f16 [TC*B][1024] = 8,388,608
static const size_t HST0_OFF   = 16777216ull;               // f16 [TC*B][256]  = 2,097,152
static const size_t HST1_OFF   = 18874368ull;               // f16 [TC*B][256]  = 2,097,152
static const size_t WHH_OFF    = 20971520ull;               // uint4 [4][16][512] = 524,288
static const size_t WIH_OFF    = WHH_OFF  + 524288ull;      // uint4 [16384]    =    262,144
static const size_t WOUT_OFF   = WIH_OFF  + 262144ull;      // f16 [128][256]   =     65,536
static const size_t BSUM_OFF   = WOUT_OFF + 65536ull;       // f32 [1024]       =      4,096
static const size_t HSTATE_OFF = BSUM_OFF + 4096ull;        // f16 [64][256]    =     32,768
static const size_t CSTATE_OFF = HSTATE_OFF + 32768ull;     // f32 [64][256]    =     65,536
static const size_t WS_NEEDED  = CSTATE_OFF + 65536ull;     // = 21,925,888

// fused-kernel dynamic LDS: consumer g-weights 128 KB + h ping-pong 1 KB
static const int SMEM_SZ = 131072 + 1024;                   // 132,096 B (<160 KB/CU)

typedef _Float16 h2 __attribute__((ext_vector_type(2)));

union U16 { uint4 u; h2 h[4]; };          // 16B <-> 4x half2
union HU  { unsigned short u; _Float16 h; };

__device__ __forceinline__ float fdot2f(h2 a, h2 b, float c) {
#if __has_builtin(__builtin_amdgcn_fdot2)
  return __builtin_amdgcn_fdot2(a, b, c, false);   // v_dot2_f32_f16, f32 accumulate
#else
  return c + (float)a.x * (float)b.x + (float)a.y * (float)b.y;
#endif
}

__device__ __forceinline__ float sigm(float x) { return 1.f / (1.f + __expf(-x)); }
__device__ __forceinline__ float tanh_fast(float x) {
  float ax = fabsf(x);
  float e  = __expf(-2.f * ax);          // in (0,1], no overflow
  float r  = (1.f - e) / (1.f + e);
  return x < 0.f ? -r : r;
}

// ---------------- K0: pack weights to f16 layouts, bias sum ----------------
// W_hh layout: uint4 index = rr*8192 + q*512 + u2, u2 = u*2+half
//   rr 0/1/2/3 -> rows u / 256+u / 768+u / 512+u  (i, f, o, g)
//   k-range of the uint4: half*128 + q*8 .. +8
// Consumer lane L has u2 == tid -> all weight/LDS accesses per-lane linear.
__global__ void k0_pack(const float* __restrict__ Whh, const float* __restrict__ Wih,
                        const float* __restrict__ Wout, const float* __restrict__ bih,
                        const float* __restrict__ bhh, uint8_t* __restrict__ ws) {
  int tid = blockIdx.x * 256 + threadIdx.x;
  if (tid < 32768) {
    int rr = tid >> 13, rem = tid & 8191;
    int q = rem >> 9, u2 = rem & 511;
    int u = u2 >> 1, hf = u2 & 1;
    int row = (rr == 0) ? u : (rr == 1) ? 256 + u : (rr == 2) ? 768 + u : 512 + u;
    int kb = hf * 128 + q * 8;
    const float4* s = (const float4*)(Whh + (size_t)row * HH + kb);
    float4 v0 = s[0], v1 = s[1];
    U16 o;
    o.h[0].x = (_Float16)v0.x; o.h[0].y = (_Float16)v0.y;
    o.h[1].x = (_Float16)v0.z; o.h[1].y = (_Float16)v0.w;
    o.h[2].x = (_Float16)v1.x; o.h[2].y = (_Float16)v1.y;
    o.h[3].x = (_Float16)v1.z; o.h[3].y = (_Float16)v1.w;
    ((uint4*)(ws + WHH_OFF))[tid] = o.u;
  } else if (tid < 65536) {                // W_out -> f16, row-major [128][256]
    int t2 = tid - 32768;
    ((_Float16*)(ws + WOUT_OFF))[t2] = (_Float16)Wout[t2];
  } else if (tid < 81920) {                // W_ih -> f16, row-major [1024][128], 8-packed
    int i = tid - 65536;
    const float4* s = (const float4*)(Wih + (size_t)i * 8);
    float4 v0 = s[0], v1 = s[1];
    U16 o;
    o.h[0].x = (_Float16)v0.x; o.h[0].y = (_Float16)v0.y;
    o.h[1].x = (_Float16)v0.z; o.h[1].y = (_Float16)v0.w;
    o.h[2].x = (_Float16)v1.x; o.h[2].y = (_Float16)v1.y;
    o.h[3].x = (_Float16)v1.z; o.h[3].y = (_Float16)v1.w;
    ((uint4*)(ws + WIH_OFF))[i] = o.u;
  } else if (tid < 82944) {                // bias sum
    int n = tid - 81920;
    ((float*)(ws + BSUM_OFF))[n] = bih[n] + bhh[n];
  }
}

// ---------------- K1: xg for chunk 0 only (later chunks made by producer wgs) ----
__global__ void __launch_bounds__(256) k1_xgemm(const float* __restrict__ x,
                                                uint8_t* __restrict__ ws) {
  const uint4* Wp   = (const uint4*)(ws + WIH_OFF);
  const float* bsum = (const float*)(ws + BSUM_OFF);
  _Float16*    xg   = (_Float16*)(ws + XG0_OFF);

  const int s = blockIdx.x >> 4;                       // col segment (64 cols), 16 segs
  const int m = ((blockIdx.x & 15) << 8) + threadIdx.x; // row 0..4095

  __shared__ uint4 wlds[1024];                         // 64 rows x 16 uint4
  __shared__ float bsl[64];
  #pragma unroll
  for (int i = 0; i < 4; ++i)
    wlds[i * 256 + threadIdx.x] = Wp[(size_t)(s << 6) * 16 + i * 256 + threadIdx.x];
  if (threadIdx.x < 64) bsl[threadIdx.x] = bsum[(s << 6) + threadIdx.x];
  __syncthreads();

  const float4* xr = (const float4*)(x + (size_t)m * IND);   // t0 = 0
  h2 xv[64];
  #pragma unroll
  for (int i = 0; i < 32; ++i) {
    float4 v = xr[i];
    xv[2*i  ].x = (_Float16)v.x; xv[2*i  ].y = (_Float16)v.y;
    xv[2*i+1].x = (_Float16)v.z; xv[2*i+1].y = (_Float16)v.w;
  }
  _Float16* xgrow = xg + (size_t)m * GG + (s << 6);
  for (int g = 0; g < 8; ++g) {
    float acc[8];
    #pragma unroll
    for (int j = 0; j < 8; ++j) {
      const uint4* wr = &wlds[(g * 8 + j) * 16];
      float a = bsl[g * 8 + j];
      #pragma unroll
      for (int q = 0; q < 16; ++q) {
        U16 w; w.u = wr[q];
        a = fdot2f(w.h[0], xv[4*q+0], a);
        a = fdot2f(w.h[1], xv[4*q+1], a);
        a = fdot2f(w.h[2], xv[4*q+2], a);
        a = fdot2f(w.h[3], xv[4*q+3], a);
      }
      acc[j] = a;
    }
    U16 o;
    #pragma unroll
    for (int p = 0; p < 4; ++p) { o.h[p].x = (_Float16)acc[2*p]; o.h[p].y = (_Float16)acc[2*p+1]; }
    *(uint4*)(xgrow + g * 8) = o.u;
  }
}

// ---------------- Fused per-chunk kernel: 3 wg roles ----------------
// grid 224 x 512 threads:
//   wg 0..63    consumer : recurrence for chunk ch (1 wg per batch element)
//   wg 64..191  producer : xg GEMM for chunk ch+1 (ping-pong buffer)
//   wg 192..223 y        : output projection of chunk ch-1 from hst ping-pong
// Consumer: lane-pair layout u=tid>>1, half=tid&1 -> both k-halves of a unit in
// adjacent lanes; partials exchanged via __shfl_xor (no LDS arrays); gates
// computed redundantly in both lanes (bitwise-identical c); h ping-pong in LDS
// -> exactly ONE __syncthreads per step. i/f/o in 192 regs (round-5 proven),
// g all in 128 KB LDS.
__global__ void __launch_bounds__(512, 2) k2_fused(const float* __restrict__ x,
                                                   uint8_t* __restrict__ ws,
                                                   const float* __restrict__ b_out,
                                                   float* __restrict__ out, int ch) {
  extern __shared__ __align__(16) uint8_t smem[];
  const int bi  = blockIdx.x;
  const int tid = threadIdx.x;

  if (bi < 64) {
    // ================= consumer =================
    if (ch >= NCH) return;
    const int b    = bi;
    const int u    = tid >> 1;                        // unit 0..255
    const int half = tid & 1;                         // k-half
    const int t0   = ch * TC;

    const uint4* WR = (const uint4*)(ws + WHH_OFF);   // [rr][q][u2]
    const uint4* WG = WR + 24576;                     // rr=3 (g rows)
    const unsigned short* xp = (const unsigned short*)(ws + ((ch & 1) ? XG1_OFF : XG0_OFF));
    _Float16* hst    = (_Float16*)(ws + ((ch & 1) ? HST1_OFF : HST0_OFF));
    _Float16* hstate = (_Float16*)(ws + HSTATE_OFF);
    float*    cstate = (float*)(ws + CSTATE_OFF);

    uint4*    gws   = (uint4*)smem;                   // [16][512] uint4 = 128 KB
    _Float16* h_lds = (_Float16*)(smem + 131072);     // [2][256] ping-pong, 1 KB

    // one-time: i/f/o half-rows into registers (192 h2); per-lane linear (u2==tid)
    h2 wi[64], wf[64], wo[64];
    #pragma unroll
    for (int q = 0; q < 16; ++q) {
      U16 a;
      a.u = WR[q * 512 + tid];
      wi[4*q+0]=a.h[0]; wi[4*q+1]=a.h[1]; wi[4*q+2]=a.h[2]; wi[4*q+3]=a.h[3];
      a.u = WR[8192 + q * 512 + tid];
      wf[4*q+0]=a.h[0]; wf[4*q+1]=a.h[1]; wf[4*q+2]=a.h[2]; wf[4*q+3]=a.h[3];
      a.u = WR[16384 + q * 512 + tid];
      wo[4*q+0]=a.h[0]; wo[4*q+1]=a.h[1]; wo[4*q+2]=a.h[2]; wo[4*q+3]=a.h[3];
    }
    // one-time: stage all g rows into LDS (linear copy)
    #pragma unroll
    for (int j = 0; j < 16; ++j) gws[j * 512 + tid] = WG[j * 512 + tid];

    if (tid < 32) {                                   // h_{-1} -> buf0
      uint4 z = make_uint4(0u, 0u, 0u, 0u);
      ((uint4*)h_lds)[tid] = (t0 == 0) ? z : ((const uint4*)(hstate + (size_t)b * HH))[tid];
    }
    float c = 0.f;
    if (t0 != 0) c = cstate[(size_t)b * HH + u];      // both lanes of pair load same c

    const size_t xrow = (size_t)b * GG;
    HU xi, xf, xgv, xo;
    xi.u  = xp[xrow + u];
    xf.u  = xp[xrow + 256 + u];
    xgv.u = xp[xrow + 512 + u];
    xo.u  = xp[xrow + 768 + u];
    __syncthreads();

    for (int tt = 0; tt < TC; ++tt) {
      float ai = 0.f, af = 0.f, ag = 0.f, ao = 0.f;
      // read h from buf[tt&1]; lane's k-half only (2 addresses per wave = free)
      const uint4* hv = ((const uint4*)h_lds) + (tt & 1) * 32 + half * 16;
      #pragma unroll
      for (int q = 0; q < 16; ++q) {
        U16 hh;  hh.u  = hv[q];
        U16 wg_; wg_.u = gws[q * 512 + tid];
        #pragma unroll
        for (int j = 0; j < 4; ++j) {
          ai = fdot2f(wi[4*q+j], hh.h[j], ai);
          af = fdot2f(wf[4*q+j], hh.h[j], af);
          ag = fdot2f(wg_.h[j],  hh.h[j], ag);
          ao = fdot2f(wo[4*q+j], hh.h[j], ao);
        }
      }
      // lane-pair partial exchange (k-half <-> k-half), commutative adds ->
      // both lanes get bitwise-identical sums
      ai += __shfl_xor(ai, 1);
      af += __shfl_xor(af, 1);
      ag += __shfl_xor(ag, 1);
      ao += __shfl_xor(ao, 1);
      float gi = sigm(ai + (float)xi.h);
      float gf = sigm(af + (float)xf.h);
      float gg = tanh_fast(ag + (float)xgv.h);
      float go = sigm(ao + (float)xo.h);
      c = gf * c + gi * gg;
      float hn = go * tanh_fast(c);
      if (half == 0) {                                // even lanes own the stores
        h_lds[((tt + 1) & 1) * HH + u] = (_Float16)hn;
        hst[((size_t)tt * BB + b) * HH + u] = (_Float16)hn;
        if (t0 + tt == TT - 1) {
          const size_t tail = (size_t)TT * BB * OUTD;
          out[tail + (size_t)b * HH + u] = hn;                       // h_T
          out[tail + (size_t)BB * HH + (size_t)b * HH + u] = c;      // c_T
        }
      }
      if (tt + 1 < TC) {                              // prefetch next step's xg
        const size_t nx = xrow + (size_t)(tt + 1) * (BB * GG);
        xi.u  = xp[nx + u];
        xf.u  = xp[nx + 256 + u];
        xgv.u = xp[nx + 512 + u];
        xo.u  = xp[nx + 768 + u];
      }
      __syncthreads();                                // new h visible; old buf free
    }

    // persist state (TC even -> final h is in buf0)
    if (tid < 32) ((uint4*)(hstate + (size_t)b * HH))[tid] = ((const uint4*)h_lds)[tid];
    if (half == 0) cstate[(size_t)b * HH + u] = c;

  } else if (bi < 192) {
    // ================= producer: xg for chunk ch+1 =================
    if (ch + 1 >= NCH) return;
    const int p    = bi - 64;
    const int seg  = p >> 3;                          // 0..15 (64-col segment)
    const int rowg = p & 7;
    const int m    = rowg * 512 + tid;                // 0..4095
    const int t0n  = (ch + 1) * TC;

    const uint4* Wp   = (const uint4*)(ws + WIH_OFF);
    const float* bsum = (const float*)(ws + BSUM_OFF);
    _Float16*    xgn  = (_Float16*)(ws + (((ch + 1) & 1) ? XG1_OFF : XG0_OFF));

    uint4* wlds = (uint4*)smem;                       // 1024 uint4 = 16 KB
    float* bsl  = (float*)(smem + 16384);
    wlds[tid]       = Wp[(size_t)(seg << 6) * 16 + tid];
    wlds[tid + 512] = Wp[(size_t)(seg << 6) * 16 + 512 + tid];
    if (tid < 64) bsl[tid] = bsum[(seg << 6) + tid];
    __syncthreads();

    const float4* xr = (const float4*)(x + ((size_t)t0n * BB + m) * IND);
    h2 xv[64];
    #pragma unroll
    for (int i = 0; i < 32; ++i) {
      float4 v = xr[i];
      xv[2*i  ].x = (_Float16)v.x; xv[2*i  ].y = (_Float16)v.y;
      xv[2*i+1].x = (_Float16)v.z; xv[2*i+1].y = (_Float16)v.w;
    }
    _Float16* xgrow = xgn + (size_t)m * GG + (seg << 6);
    for (int g = 0; g < 8; ++g) {
      float acc[8];
      #pragma unroll
      for (int j = 0; j < 8; ++j) {
        const uint4* wr = &wlds[(g * 8 + j) * 16];
        float a = bsl[g * 8 + j];
        #pragma unroll
        for (int q = 0; q < 16; ++q) {
          U16 w; w.u = wr[q];
          a = fdot2f(w.h[0], xv[4*q+0], a);
          a = fdot2f(w.h[1], xv[4*q+1], a);
          a = fdot2f(w.h[2], xv[4*q+2], a);
          a = fdot2f(w.h[3], xv[4*q+3], a);
        }
        acc[j] = a;
      }
      U16 o;
      #pragma unroll
      for (int pk = 0; pk < 4; ++pk) { o.h[pk].x = (_Float16)acc[2*pk]; o.h[pk].y = (_Float16)acc[2*pk+1]; }
      *(uint4*)(xgrow + g * 8) = o.u;
    }

  } else {
    // ================= y: output projection for chunk ch-1 =================
    if (ch < 1) return;
    const int yb   = bi - 192;                        // 0..31
    const int seg  = yb & 15;                         // 8-col segment
    const int rowg = yb >> 4;                         // 0..1
    const int t0p  = (ch - 1) * TC;

    const _Float16* hstp = (const _Float16*)(ws + (((ch - 1) & 1) ? HST1_OFF : HST0_OFF));
    const uint4* WO = (const uint4*)(ws + WOUT_OFF);  // [128][32] uint4

    uint4* wlds = (uint4*)smem;                       // 256 uint4 = 4 KB
    float* bsl  = (float*)(smem + 4096);
    if (tid < 256) wlds[tid] = WO[(size_t)(seg * 8) * 32 + tid];
    if (tid < 8)   bsl[tid]  = b_out[seg * 8 + tid];
    __syncthreads();

    #pragma unroll
    for (int rr = 0; rr < 4; ++rr) {                  // 4 rows per thread
      const int r = rowg * 2048 + rr * 512 + tid;     // 0..4095
      const uint4* hr = (const uint4*)(hstp + (size_t)r * HH);
      float acc[8];
      #pragma unroll
      for (int j = 0; j < 8; ++j) acc[j] = bsl[j];
      #pragma unroll 4
      for (int q = 0; q < 32; ++q) {
        U16 hh; hh.u = hr[q];
        #pragma unroll
        for (int j = 0; j < 8; ++j) {
          U16 w; w.u = wlds[j * 32 + q];
          acc[j] = fdot2f(w.h[0], hh.h[0], acc[j]);
          acc[j] = fdot2f(w.h[1], hh.h[1], acc[j]);
          acc[j] = fdot2f(w.h[2], hh.h[2], acc[j]);
          acc[j] = fdot2f(w.h[3], hh.h[3], acc[j]);
        }
      }
      float* orow = out + ((size_t)t0p * BB + r) * OUTD + seg * 8;
      *(float4*)(orow)     = make_float4(acc[0], acc[1], acc[2], acc[3]);
      *(float4*)(orow + 4) = make_float4(acc[4], acc[5], acc[6], acc[7]);
    }
  }
}

extern "C" void kernel_launch(void* const* d_in, const int* in_sizes, int n_in,
                              void* d_out, int out_size, void* d_ws, size_t ws_size,
                              hipStream_t stream) {
  const float* input = (const float*)d_in[0];
  const float* W_ih  = (const float*)d_in[1];
  const float* W_hh  = (const float*)d_in[2];
  const float* b_ih  = (const float*)d_in[3];
  const float* b_hh  = (const float*)d_in[4];
  const float* W_out = (const float*)d_in[5];
  const float* b_out = (const float*)d_in[6];
  float*   out = (float*)d_out;
  uint8_t* ws  = (uint8_t*)d_ws;

  if (ws_size < WS_NEEDED) return;   // fail validation cleanly instead of faulting

  // allow 129 KB dynamic LDS (gfx950: 160 KB/CU); host-side + idempotent ->
  // safe under graph capture (proven rounds 5 & 8).
  hipFuncSetAttribute((const void*)k2_fused,
                      hipFuncAttributeMaxDynamicSharedMemorySize, SMEM_SZ);

  hipLaunchKernelGGL(k0_pack,  dim3(324), dim3(256), 0, stream,
                     W_hh, W_ih, W_out, b_ih, b_hh, ws);
  hipLaunchKernelGGL(k1_xgemm, dim3(256), dim3(256), 0, stream, input, ws); // chunk 0 xg
  for (int ch = 0; ch <= NCH; ++ch) {   // ch==NCH: only y-role (last chunk's output)
    hipLaunchKernelGGL(k2_fused, dim3(224), dim3(512), SMEM_SZ, stream,
                       input, ws, b_out, out, ch);
  }
}